// Round 7
// baseline (28770.798 us; speedup 1.0000x reference)
//
#include <hip/hip_runtime.h>
#include <stdint.h>

typedef unsigned long long u64;
typedef unsigned int u32;

#define HEADS 16
#define SEQ   4096
#define DH    128
#define TOPK  64
#define NT    256
#define KPT   16      // keys per thread = SEQ/NT

// Map float to order-preserving u32 (IEEE total order for finite values).
__device__ __forceinline__ u32 sortable32(float x) {
  u32 b = __float_as_uint(x);
  return (b & 0x80000000u) ? ~b : (b | 0x80000000u);
}

__device__ __forceinline__ u64 umax64(u64 a, u64 b) { return a > b ? a : b; }

__global__ __launch_bounds__(NT) void si_topk_kernel(
    const float* __restrict__ qg,
    const float* __restrict__ kg,
    int* __restrict__ outg)
{
  #pragma clang fp contract(off)

  __shared__ float qs[DH];
  __shared__ u64   wmax[NT / 64];

  const int t = threadIdx.x;
  const unsigned bid = blockIdx.x;
  // XCD-pinned swizzle: head = (bid&7) + 8*(bid>>15); 2 heads (4MB K) per XCD L2.
  const int h  = (int)(bid & 7u) + 8 * (int)(bid >> 15);
  const int qi = (int)((bid >> 3) & 4095u);

  const float* __restrict__ qrow = qg + ((size_t)h << 19) + ((size_t)qi << 7);
  const float* __restrict__ kh   = kg + ((size_t)h << 19);

  if (t < DH) qs[t] = qrow[t];
  __syncthreads();

  // XLA algebraic-simplifier semantics: divide(x, c) -> multiply(x, 1/c),
  // reciprocal computed once in f32. Constant-folded with IEEE rounding:
  const float RECIP = 1.0f / 11.313708498984761f;   // f32(1 / f32(sqrt(128)))

  // ---- phase 1: GEMM-style fp32 scores (validated direction, round 6) ----
  // One sequential FMA chain per score, d = 0..127 ascending, then scale by
  // multiply-with-reciprocal (this round's single change vs. round 6's divide).
  // Tie-break: lax.top_k = lowest index first -> pack (4095 - j) low bits.
  u64 kreg[KPT];
  #pragma unroll
  for (int mg = 0; mg < KPT / 4; ++mg) {
    const int j0 = t + NT * (4 * mg + 0);
    const int j1 = t + NT * (4 * mg + 1);
    const int j2 = t + NT * (4 * mg + 2);
    const int j3 = t + NT * (4 * mg + 3);
    const float4* __restrict__ r0 = (const float4*)(kh + ((size_t)j0 << 7));
    const float4* __restrict__ r1 = (const float4*)(kh + ((size_t)j1 << 7));
    const float4* __restrict__ r2 = (const float4*)(kh + ((size_t)j2 << 7));
    const float4* __restrict__ r3 = (const float4*)(kh + ((size_t)j3 << 7));
    float a0 = 0.f, a1 = 0.f, a2 = 0.f, a3 = 0.f;
    #pragma unroll
    for (int c = 0; c < DH / 4; ++c) {   // ascending d, strict chain per row
      const float4 qv = *(const float4*)&qs[4 * c];
      const float4 w0 = r0[c], w1 = r1[c], w2 = r2[c], w3 = r3[c];
      a0 = __builtin_fmaf(w0.x, qv.x, a0);
      a0 = __builtin_fmaf(w0.y, qv.y, a0);
      a0 = __builtin_fmaf(w0.z, qv.z, a0);
      a0 = __builtin_fmaf(w0.w, qv.w, a0);
      a1 = __builtin_fmaf(w1.x, qv.x, a1);
      a1 = __builtin_fmaf(w1.y, qv.y, a1);
      a1 = __builtin_fmaf(w1.z, qv.z, a1);
      a1 = __builtin_fmaf(w1.w, qv.w, a1);
      a2 = __builtin_fmaf(w2.x, qv.x, a2);
      a2 = __builtin_fmaf(w2.y, qv.y, a2);
      a2 = __builtin_fmaf(w2.z, qv.z, a2);
      a2 = __builtin_fmaf(w2.w, qv.w, a2);
      a3 = __builtin_fmaf(w3.x, qv.x, a3);
      a3 = __builtin_fmaf(w3.y, qv.y, a3);
      a3 = __builtin_fmaf(w3.z, qv.z, a3);
      a3 = __builtin_fmaf(w3.w, qv.w, a3);
    }
    const float s0 = a0 * RECIP;
    const float s1 = a1 * RECIP;
    const float s2 = a2 * RECIP;
    const float s3 = a3 * RECIP;
    kreg[4 * mg + 0] = ((u64)sortable32(s0) << 32) | (u64)(4095 - j0);
    kreg[4 * mg + 1] = ((u64)sortable32(s1) << 32) | (u64)(4095 - j1);
    kreg[4 * mg + 2] = ((u64)sortable32(s2) << 32) | (u64)(4095 - j2);
    kreg[4 * mg + 3] = ((u64)sortable32(s3) << 32) | (u64)(4095 - j3);
  }

  // cached per-thread max
  u64 lmax = kreg[0];
  #pragma unroll
  for (int mm = 1; mm < KPT; ++mm) lmax = umax64(lmax, kreg[mm]);

  const size_t obase = ((((size_t)h << 12) | (size_t)qi) << 6);

  // ---- phase 2: 64 sequential argmax passes (validated rounds 2/3) ----
  for (int r = 0; r < TOPK; ++r) {
    u64 v = lmax;
    #pragma unroll
    for (int m = 1; m < 64; m <<= 1) {
      unsigned lo = (unsigned)(v & 0xffffffffULL);
      unsigned hi = (unsigned)(v >> 32);
      lo = (unsigned)__shfl_xor((int)lo, m, 64);
      hi = (unsigned)__shfl_xor((int)hi, m, 64);
      v = umax64(v, ((u64)hi << 32) | (u64)lo);
    }
    if ((t & 63) == 0) wmax[t >> 6] = v;
    __syncthreads();
    const u64 gmax = umax64(umax64(wmax[0], wmax[1]), umax64(wmax[2], wmax[3]));
    __syncthreads();

    if (lmax == gmax) {   // unique winner: keys are globally distinct
      outg[obase + (size_t)r] = 4095 - (int)(gmax & 0xFFFULL);
      #pragma unroll
      for (int mm = 0; mm < KPT; ++mm)
        if (kreg[mm] == gmax) kreg[mm] = 0ULL;
      u64 nm = kreg[0];
      #pragma unroll
      for (int mm = 1; mm < KPT; ++mm) nm = umax64(nm, kreg[mm]);
      lmax = nm;
    }
  }
}

extern "C" void kernel_launch(void* const* d_in, const int* in_sizes, int n_in,
                              void* d_out, int out_size, void* d_ws, size_t ws_size,
                              hipStream_t stream) {
  const float* q = (const float*)d_in[0];
  const float* k = (const float*)d_in[1];
  int* out = (int*)d_out;
  dim3 grid(HEADS * SEQ);   // 65536 blocks: one per (head, query) row
  si_topk_kernel<<<grid, NT, 0, stream>>>(q, k, out);
}

// Round 8
// 6047.991 us; speedup vs baseline: 4.7571x; 4.7571x over previous
//
#include <hip/hip_runtime.h>
#include <stdint.h>

typedef unsigned long long u64;
typedef unsigned int u32;

#define HEADS 16
#define SEQ   4096
#define DH    128
#define TOPK  64
#define NT    256
#define QB    8          // q-rows per block
#define KT    512        // k-rows per LDS tile
#define DP    32         // d-columns per stage round
#define CAND_CAP 224
#define NBIN  32

// Map float to order-preserving u32 (IEEE total order for finite values).
__device__ __forceinline__ u32 sortable32(float x) {
  u32 b = __float_as_uint(x);
  return (b & 0x80000000u) ? ~b : (b | 0x80000000u);
}
__device__ __forceinline__ u64 umax64(u64 a, u64 b) { return a > b ? a : b; }

// Bin function MUST be evaluated identically in pass A and pass B (same code).
__device__ __forceinline__ int binOf(float s, float si) {
  int b = (int)floorf(s * si * 4.0f) + 8;    // z in [-2, +6) -> bins 0..31
  return min(max(b, 0), NBIN - 1);
}

__global__ __launch_bounds__(NT, 2) void si_topk_kernel(
    const float* __restrict__ qg,
    const float* __restrict__ kg,
    int* __restrict__ outg)
{
  __shared__ float4 tile[KT * (DP / 4)];   // 64 KB, XOR-swizzled 16B granules
  __shared__ u64    cand[QB][CAND_CAP];    // 14 KB
  __shared__ u32    hist[QB][NBIN];        // 1 KB
  __shared__ u32    cnt[QB];
  __shared__ int    bstar[QB];
  __shared__ float  sinv[QB];

  const int t = threadIdx.x;
  const unsigned bid = blockIdx.x;
  // XCD pinning: 8192 blocks, bid&7 = XCD (round-robin). Heads {x, x+8} -> XCD x:
  // 2 heads * 2MB K = 4MB = one XCD's L2.
  const int h  = (int)(bid & 7u) + 8 * (int)(bid >> 12);
  const int qc = (int)((bid >> 3) & 511u);

  const float* __restrict__ qp = qg + ((size_t)h << 19) + ((size_t)(qc * QB) << 7);
  const float* __restrict__ kh = kg + ((size_t)h << 19);

  const float RECIP = 1.0f / 11.313708498984761f;   // validated round-7 scale

  // ---- init: sigma_inv per row (binning only - self-consistent), hist/cnt ----
  if (t < QB) {
    float s2 = 0.f;
    for (int d = 0; d < DH; ++d) {
      const float q = qp[t * DH + d];
      s2 = __builtin_fmaf(q, q, s2);
    }
    sinv[t] = 1.0f / (sqrtf(fmaxf(s2, 1e-30f)) * RECIP);
    cnt[t] = 0;
  }
  for (int i = t; i < QB * NBIN; i += NT) ((u32*)hist)[i] = 0;
  __syncthreads();

  // ---- two passes: A = histogram counts, B = candidate collection ----
  for (int pass = 0; pass < 2; ++pass) {
    for (int kt = 0; kt < SEQ / KT; ++kt) {
      float acc[QB][2];
      #pragma unroll
      for (int qr = 0; qr < QB; ++qr) { acc[qr][0] = 0.f; acc[qr][1] = 0.f; }

      for (int dp = 0; dp < DH / DP; ++dp) {
        __syncthreads();   // previous round's readers done before overwrite
        // stage [512 rows][32 d] coalesced (wave = 8 full 128B lines), swizzled
        #pragma unroll
        for (int g = 0; g < 2; ++g) {
          float4 v[8];
          #pragma unroll
          for (int i = 0; i < 8; ++i) {
            const int a = (g * 8 + i) * NT + t;       // 16B-granule id 0..4095
            const int row = a >> 3, s = a & 7;
            v[i] = *(const float4*)&kh[((size_t)(kt * KT + row) << 7) + dp * DP + s * 4];
          }
          #pragma unroll
          for (int i = 0; i < 8; ++i) {
            const int a = (g * 8 + i) * NT + t;
            const int row = a >> 3, s = a & 7;
            tile[row * 8 + (s ^ (row & 7))] = v[i];   // XOR bank swizzle
          }
        }
        __syncthreads();

        // compute: 8 c-steps of 4 d each; thread owns k-rows {t, t+256}
        #pragma unroll
        for (int c = 0; c < DP / 4; ++c) {
          const float4 k0 = tile[t * 8 + (c ^ (t & 7))];
          const float4 k1 = tile[(t + 256) * 8 + (c ^ (t & 7))];  // (t+256)&7 == t&7
          const int dbase = dp * DP + c * 4;
          #pragma unroll
          for (int qr = 0; qr < QB; ++qr) {
            // block-uniform q loads -> scalar (SGPR) path
            const float q0 = qp[qr * DH + dbase + 0];
            const float q1 = qp[qr * DH + dbase + 1];
            const float q2 = qp[qr * DH + dbase + 2];
            const float q3 = qp[qr * DH + dbase + 3];
            // exact r7 chain: d ascending, one accumulator per dot
            acc[qr][0] = __builtin_fmaf(k0.x, q0, acc[qr][0]);
            acc[qr][0] = __builtin_fmaf(k0.y, q1, acc[qr][0]);
            acc[qr][0] = __builtin_fmaf(k0.z, q2, acc[qr][0]);
            acc[qr][0] = __builtin_fmaf(k0.w, q3, acc[qr][0]);
            acc[qr][1] = __builtin_fmaf(k1.x, q0, acc[qr][1]);
            acc[qr][1] = __builtin_fmaf(k1.y, q1, acc[qr][1]);
            acc[qr][1] = __builtin_fmaf(k1.z, q2, acc[qr][1]);
            acc[qr][1] = __builtin_fmaf(k1.w, q3, acc[qr][1]);
          }
        }
      }

      // finalize this k-tile's 16 dots
      #pragma unroll
      for (int e = 0; e < 2; ++e) {
        const int j = kt * KT + t + e * 256;
        #pragma unroll
        for (int qr = 0; qr < QB; ++qr) {
          const float s = acc[qr][e] * RECIP;        // validated scale
          const int b = binOf(s, sinv[qr]);
          if (pass == 0) {
            atomicAdd(&hist[qr][b], 1u);
          } else if (b >= bstar[qr]) {
            const u32 p = atomicAdd(&cnt[qr], 1u);
            if (p < CAND_CAP)
              cand[qr][p] = ((u64)sortable32(s) << 32) | (u64)(4095 - j);
          }
        }
      }
    }

    __syncthreads();
    if (pass == 0 && t < QB) {
      // b* = max bin with suffix count >= 64  (suffix(0)=4096 so always exists)
      u32 suf = 0; int bs = 0;
      for (int b = NBIN - 1; b >= 0; --b) {
        suf += hist[t][b];
        if (suf >= TOPK) { bs = b; break; }
      }
      bstar[t] = bs;
      cnt[t] = 0;
    }
    __syncthreads();
  }

  // ---- selection: per wave, 2 rows; 64 argmax passes (validated r2-r7) ----
  const int wid = t >> 6, lane = t & 63;
  for (int row = wid; row < QB; row += 4) {
    const u32 n = min(cnt[row], (u32)CAND_CAP);   // n >= 64 by b* construction
    u64 slot[4];
    #pragma unroll
    for (int i = 0; i < 4; ++i) {
      const int idx = lane + 64 * i;
      slot[i] = (idx < (int)n) ? cand[row][idx] : 0ULL;
    }
    const size_t obase = (((size_t)h << 12) | (size_t)(qc * QB + row)) << 6;
    for (int r = 0; r < TOPK; ++r) {
      const u64 lm = umax64(umax64(slot[0], slot[1]), umax64(slot[2], slot[3]));
      u64 v = lm;
      #pragma unroll
      for (int m = 1; m < 64; m <<= 1) {
        unsigned lo = (unsigned)(v & 0xffffffffULL);
        unsigned hi = (unsigned)(v >> 32);
        lo = (unsigned)__shfl_xor((int)lo, m, 64);
        hi = (unsigned)__shfl_xor((int)hi, m, 64);
        v = umax64(v, ((u64)hi << 32) | (u64)lo);
      }
      if (lm == v && v != 0ULL) {     // unique winner: keys globally distinct
        outg[obase + r] = 4095 - (int)(v & 0xFFFULL);
        #pragma unroll
        for (int i = 0; i < 4; ++i) if (slot[i] == v) slot[i] = 0ULL;
      }
    }
  }
}

extern "C" void kernel_launch(void* const* d_in, const int* in_sizes, int n_in,
                              void* d_out, int out_size, void* d_ws, size_t ws_size,
                              hipStream_t stream) {
  const float* q = (const float*)d_in[0];
  const float* k = (const float*)d_in[1];
  int* out = (int*)d_out;
  dim3 grid(HEADS * (SEQ / QB) * 8 / 8);   // 16 heads x 512 q-chunks = 8192
  si_topk_kernel<<<dim3(8192), NT, 0, stream>>>(q, k, out);
}

// Round 9
// 5189.902 us; speedup vs baseline: 5.5436x; 1.1653x over previous
//
#include <hip/hip_runtime.h>
#include <stdint.h>

typedef unsigned long long u64;
typedef unsigned int u32;
typedef unsigned short u16;

#define HEADS 16
#define SEQ   4096
#define DH    128
#define TOPK  64
#define NT    256
#define QB    8          // q-rows per block
#define KT    512        // k-rows per LDS tile
#define DP    32         // d-columns per stage round
#define CAND_CAP 216
#define NBIN  32

// Map float to order-preserving u32 (IEEE total order for finite values).
__device__ __forceinline__ u32 sortable32(float x) {
  u32 b = __float_as_uint(x);
  return (b & 0x80000000u) ? ~b : (b | 0x80000000u);
}
__device__ __forceinline__ u64 umax64(u64 a, u64 b) { return a > b ? a : b; }

// Bin function MUST be evaluated identically in pass A and pass B (same code).
__device__ __forceinline__ int binOf(float s, float si) {
  int b = (int)floorf(s * si * 4.0f) + 8;    // z in [-2, +6) -> bins 0..31
  return min(max(b, 0), NBIN - 1);
}

__global__ __launch_bounds__(NT, 2) void si_topk_kernel(
    const float* __restrict__ qg,
    const float* __restrict__ kg,
    int* __restrict__ outg)
{
  #pragma clang fp contract(off)

  __shared__ float4 tile[KT * (DP / 4)];   // 64 KB, XOR-swizzled 16B granules
  __shared__ float4 qs4[QB * DH / 4];      // 4 KB: q rows staged once
  __shared__ u32    candS[QB][CAND_CAP];   // 6.75 KB: sortable32 scores
  __shared__ u16    candJ[QB][CAND_CAP];   // 3.375 KB: k-indices
  __shared__ u32    hist[QB][NBIN];        // 1 KB
  __shared__ u32    cnt[QB];
  __shared__ int    bstar[QB];
  __shared__ float  sinv[QB];

  const int t = threadIdx.x;
  const unsigned bid = blockIdx.x;
  // XCD pinning: bid&7 = XCD; heads {x, x+8} -> XCD x (2 heads * 2MB = one L2).
  const int h  = (int)(bid & 7u) + 8 * (int)(bid >> 12);
  const int qc = (int)((bid >> 3) & 511u);

  const float* __restrict__ qp = qg + ((size_t)h << 19) + ((size_t)(qc * QB) << 7);
  const float* __restrict__ kh = kg + ((size_t)h << 19);

  const float RECIP = 1.0f / 11.313708498984761f;   // validated round-7 scale

  // ---- stage q once: 8 rows x 128 = 256 float4, one per thread (coalesced) ----
  qs4[t] = ((const float4*)qp)[t];
  if (t < QB) cnt[t] = 0;
  for (int i = t; i < QB * NBIN; i += NT) ((u32*)hist)[i] = 0;
  __syncthreads();

  // sigma_inv per row (binning only - self-consistent across both passes)
  if (t < QB) {
    const float* qrow = (const float*)&qs4[t * (DH / 4)];
    float s2 = 0.f;
    for (int d = 0; d < DH; ++d) s2 = __builtin_fmaf(qrow[d], qrow[d], s2);
    sinv[t] = 1.0f / (sqrtf(fmaxf(s2, 1e-30f)) * RECIP);
  }
  __syncthreads();

  // ---- two passes: A = histogram counts, B = candidate collection ----
  for (int pass = 0; pass < 2; ++pass) {
    for (int kt = 0; kt < SEQ / KT; ++kt) {
      float acc[QB][2];
      #pragma unroll
      for (int qr = 0; qr < QB; ++qr) { acc[qr][0] = 0.f; acc[qr][1] = 0.f; }

      for (int dp = 0; dp < DH / DP; ++dp) {
        __syncthreads();   // previous round's readers done before overwrite
        // stage [512 rows][32 d] coalesced (wave = 8 full 128B lines), swizzled
        #pragma unroll
        for (int g = 0; g < 2; ++g) {
          float4 v[8];
          #pragma unroll
          for (int i = 0; i < 8; ++i) {
            const int a = (g * 8 + i) * NT + t;       // 16B-granule id 0..4095
            const int row = a >> 3, s = a & 7;
            v[i] = *(const float4*)&kh[((size_t)(kt * KT + row) << 7) + dp * DP + s * 4];
          }
          #pragma unroll
          for (int i = 0; i < 8; ++i) {
            const int a = (g * 8 + i) * NT + t;
            const int row = a >> 3, s = a & 7;
            tile[row * 8 + (s ^ (row & 7))] = v[i];   // XOR bank swizzle
          }
        }
        __syncthreads();

        // compute: 8 c-steps of 4 d each; thread owns k-rows {t, t+256}
        #pragma unroll
        for (int c = 0; c < DP / 4; ++c) {
          const float4 k0 = tile[t * 8 + (c ^ (t & 7))];
          const float4 k1 = tile[(t + 256) * 8 + (c ^ (t & 7))];  // (t+256)&7 == t&7
          const int dbase4 = dp * (DP / 4) + c;       // float4 index into q row
          #pragma unroll
          for (int qr = 0; qr < QB; ++qr) {
            // wave-uniform LDS broadcast read (conflict-free, DS pipe only)
            const float4 qv = qs4[qr * (DH / 4) + dbase4];
            // exact r7 chain: d ascending, one accumulator per dot
            acc[qr][0] = __builtin_fmaf(k0.x, qv.x, acc[qr][0]);
            acc[qr][0] = __builtin_fmaf(k0.y, qv.y, acc[qr][0]);
            acc[qr][0] = __builtin_fmaf(k0.z, qv.z, acc[qr][0]);
            acc[qr][0] = __builtin_fmaf(k0.w, qv.w, acc[qr][0]);
            acc[qr][1] = __builtin_fmaf(k1.x, qv.x, acc[qr][1]);
            acc[qr][1] = __builtin_fmaf(k1.y, qv.y, acc[qr][1]);
            acc[qr][1] = __builtin_fmaf(k1.z, qv.z, acc[qr][1]);
            acc[qr][1] = __builtin_fmaf(k1.w, qv.w, acc[qr][1]);
          }
        }
      }

      // finalize this k-tile's 16 dots
      #pragma unroll
      for (int e = 0; e < 2; ++e) {
        const int j = kt * KT + t + e * 256;
        #pragma unroll
        for (int qr = 0; qr < QB; ++qr) {
          const float s = acc[qr][e] * RECIP;        // validated scale
          const int b = binOf(s, sinv[qr]);
          if (pass == 0) {
            atomicAdd(&hist[qr][b], 1u);
          } else if (b >= bstar[qr]) {
            const u32 p = atomicAdd(&cnt[qr], 1u);
            if (p < CAND_CAP) {
              candS[qr][p] = sortable32(s);
              candJ[qr][p] = (u16)j;
            }
          }
        }
      }
    }

    __syncthreads();
    if (pass == 0 && t < QB) {
      // b* = max bin with suffix count >= 64  (suffix(0)=4096 so always exists)
      u32 suf = 0; int bs = 0;
      for (int b = NBIN - 1; b >= 0; --b) {
        suf += hist[t][b];
        if (suf >= TOPK) { bs = b; break; }
      }
      bstar[t] = bs;
      cnt[t] = 0;
    }
    __syncthreads();
  }

  // ---- selection: per wave, 2 rows; 64 argmax passes (validated r2-r8) ----
  const int wid = t >> 6, lane = t & 63;
  for (int row = wid; row < QB; row += 4) {
    const u32 n = min(cnt[row], (u32)CAND_CAP);   // n >= 64 by b* construction
    u64 slot[4];
    #pragma unroll
    for (int i = 0; i < 4; ++i) {
      const int idx = lane + 64 * i;
      u64 key = 0ULL;
      if (idx < (int)n)
        key = ((u64)candS[row][idx] << 32) | (u64)(4095 - (int)candJ[row][idx]);
      slot[i] = key;
    }
    const size_t obase = (((size_t)h << 12) | (size_t)(qc * QB + row)) << 6;
    for (int r = 0; r < TOPK; ++r) {
      const u64 lm = umax64(umax64(slot[0], slot[1]), umax64(slot[2], slot[3]));
      u64 v = lm;
      #pragma unroll
      for (int m = 1; m < 64; m <<= 1) {
        unsigned lo = (unsigned)(v & 0xffffffffULL);
        unsigned hi = (unsigned)(v >> 32);
        lo = (unsigned)__shfl_xor((int)lo, m, 64);
        hi = (unsigned)__shfl_xor((int)hi, m, 64);
        v = umax64(v, ((u64)hi << 32) | (u64)lo);
      }
      if (lm == v && v != 0ULL) {     // unique winner: keys globally distinct
        outg[obase + r] = 4095 - (int)(v & 0xFFFULL);
        #pragma unroll
        for (int i = 0; i < 4; ++i) if (slot[i] == v) slot[i] = 0ULL;
      }
    }
  }
}

extern "C" void kernel_launch(void* const* d_in, const int* in_sizes, int n_in,
                              void* d_out, int out_size, void* d_ws, size_t ws_size,
                              hipStream_t stream) {
  const float* q = (const float*)d_in[0];
  const float* k = (const float*)d_in[1];
  int* out = (int*)d_out;
  si_topk_kernel<<<dim3(8192), NT, 0, stream>>>(q, k, out);
}

// Round 10
// 2933.870 us; speedup vs baseline: 9.8064x; 1.7690x over previous
//
#include <hip/hip_runtime.h>
#include <stdint.h>

typedef unsigned long long u64;
typedef unsigned int u32;
typedef unsigned short u16;

#define HEADS 16
#define SEQ   4096
#define DH    128
#define TOPK  64
#define NT    512
#define QB    32         // q-rows per block
#define KT    512        // k-rows per LDS tile
#define DP    32         // d-columns per stage round (full 128B line per row)
#define QBT   8          // q-rows per thread
#define KRT   4          // k-rows per thread (consecutive)
#define CAP   224
#define ZINIT 1.8f

// Map float to order-preserving u32 (IEEE total order for finite values).
__device__ __forceinline__ u32 sortable32(float x) {
  u32 b = __float_as_uint(x);
  return (b & 0x80000000u) ? ~b : (b | 0x80000000u);
}
__device__ __forceinline__ u64 umax64(u64 a, u64 b) { return a > b ? a : b; }

__global__ __launch_bounds__(NT, 2) void si_topk_kernel(
    const float* __restrict__ qg,
    const float* __restrict__ kg,
    int* __restrict__ outg)
{
  #pragma clang fp contract(off)

  __shared__ float4 tile[KT * (DP / 4)];   // 64 KB, swizzle: g ^ ((row>>2)&7)
  __shared__ float4 qs4[QB * (DH / 4)];    // 16 KB
  __shared__ u32    candS[QB][CAP];        // 28 KB
  __shared__ u16    candJ[QB][CAP];        // 14 KB
  __shared__ u32    cnt[QB];
  __shared__ u32    done[QB];
  __shared__ float  thrv[QB], zlo[QB], zhi[QB], zc[QB], snrm[QB];
  __shared__ int    s_more;

  const int t = threadIdx.x;
  const unsigned bid = blockIdx.x;
  // bid&7 == h&7 (since 16*qc = 0 mod 8): heads {x, x+8} pinned to XCD x.
  const int h  = (int)(bid & 15u);
  const int qc = (int)(bid >> 4);          // 0..127

  const int qs = t >> 7;                   // 0..3  (uniform per wave)
  const int kid = t & 127;                 // 0..127: owns k-rows 4*kid..4*kid+3

  const float* __restrict__ qp = qg + ((size_t)h << 19) + ((size_t)(qc * QB) << 7);
  const float* __restrict__ kh = kg + ((size_t)h << 19);

  const float RECIP = 1.0f / 11.313708498984761f;   // validated round-7 scale

  // ---- stage q once: 32 rows x 128 = 1024 float4 (coalesced) ----
  #pragma unroll
  for (int i = 0; i < 2; ++i) qs4[i * NT + t] = ((const float4*)qp)[i * NT + t];
  if (t < QB) { done[t] = 0; cnt[t] = 0; }
  __syncthreads();

  // per-row sigma = ||q||/sqrt(128) (threshold only; retry makes it safe)
  if (t < QB) {
    const float* qrow = (const float*)&qs4[t * (DH / 4)];
    float s2 = 0.f;
    for (int d = 0; d < DH; ++d) s2 = __builtin_fmaf(qrow[d], qrow[d], s2);
    const float sig = sqrtf(fmaxf(s2, 1e-30f)) * RECIP;
    snrm[t] = sig;
    zlo[t] = 0.0f; zhi[t] = 8.0f; zc[t] = ZINIT;
    thrv[t] = ZINIT * sig;
  }
  __syncthreads();

  // ---- single-pass collect with deterministic bisection retry ----
  for (int attempt = 0; attempt < 24; ++attempt) {
    if (t < QB && !done[t]) cnt[t] = 0;
    __syncthreads();

    for (int kt = 0; kt < SEQ / KT; ++kt) {
      float acc[QBT][KRT];
      #pragma unroll
      for (int qr = 0; qr < QBT; ++qr)
        #pragma unroll
        for (int e = 0; e < KRT; ++e) acc[qr][e] = 0.f;

      for (int dp = 0; dp < DH / DP; ++dp) {
        __syncthreads();   // previous round's readers done before overwrite
        // stage [512 rows][32 d]: full 128B line per row, conflict-free write
        float4 v[8];
        #pragma unroll
        for (int i = 0; i < 8; ++i) {
          const int a = i * NT + t;            // granule 0..4095
          const int row = a >> 3, s = a & 7;
          v[i] = *(const float4*)&kh[((size_t)(kt * KT + row) << 7) + dp * DP + s * 4];
        }
        #pragma unroll
        for (int i = 0; i < 8; ++i) {
          const int a = i * NT + t;
          const int row = a >> 3, s = a & 7;
          tile[row * 8 + (s ^ ((row >> 2) & 7))] = v[i];
        }
        __syncthreads();

        const int swz = kid & 7;               // ((4*kid+e)>>2)&7 == kid&7
        #pragma unroll
        for (int c = 0; c < DP / 4; ++c) {
          const int cs = c ^ swz;
          const float4 k0 = tile[(kid * 4 + 0) * 8 + cs];
          const float4 k1 = tile[(kid * 4 + 1) * 8 + cs];
          const float4 k2 = tile[(kid * 4 + 2) * 8 + cs];
          const float4 k3 = tile[(kid * 4 + 3) * 8 + cs];
          #pragma unroll
          for (int qr = 0; qr < QBT; ++qr) {
            // wave-uniform LDS broadcast (qs, qr, dp, c uniform per wave)
            const float4 qv = qs4[(qs * QBT + qr) * (DH / 4) + dp * (DP / 4) + c];
            // exact validated chain: d ascending, one accumulator per dot
            acc[qr][0] = __builtin_fmaf(k0.x, qv.x, acc[qr][0]);
            acc[qr][0] = __builtin_fmaf(k0.y, qv.y, acc[qr][0]);
            acc[qr][0] = __builtin_fmaf(k0.z, qv.z, acc[qr][0]);
            acc[qr][0] = __builtin_fmaf(k0.w, qv.w, acc[qr][0]);
            acc[qr][1] = __builtin_fmaf(k1.x, qv.x, acc[qr][1]);
            acc[qr][1] = __builtin_fmaf(k1.y, qv.y, acc[qr][1]);
            acc[qr][1] = __builtin_fmaf(k1.z, qv.z, acc[qr][1]);
            acc[qr][1] = __builtin_fmaf(k1.w, qv.w, acc[qr][1]);
            acc[qr][2] = __builtin_fmaf(k2.x, qv.x, acc[qr][2]);
            acc[qr][2] = __builtin_fmaf(k2.y, qv.y, acc[qr][2]);
            acc[qr][2] = __builtin_fmaf(k2.z, qv.z, acc[qr][2]);
            acc[qr][2] = __builtin_fmaf(k2.w, qv.w, acc[qr][2]);
            acc[qr][3] = __builtin_fmaf(k3.x, qv.x, acc[qr][3]);
            acc[qr][3] = __builtin_fmaf(k3.y, qv.y, acc[qr][3]);
            acc[qr][3] = __builtin_fmaf(k3.z, qv.z, acc[qr][3]);
            acc[qr][3] = __builtin_fmaf(k3.w, qv.w, acc[qr][3]);
          }
        }
      }

      // finalize this k-tile's 32 dots per thread
      #pragma unroll
      for (int qr = 0; qr < QBT; ++qr) {
        const int row = qs * QBT + qr;
        const bool act = (done[row] == 0);
        const float thr = thrv[row];
        #pragma unroll
        for (int e = 0; e < KRT; ++e) {
          const float s = acc[qr][e] * RECIP;     // validated scale
          if (act && s >= thr) {
            const u32 p = atomicAdd(&cnt[row], 1u);
            if (p < CAP) {
              candS[row][p] = sortable32(s);
              candJ[row][p] = (u16)(kt * KT + kid * 4 + e);
            }
          }
        }
      }
    }

    __syncthreads();
    if (t == 0) s_more = 0;
    __syncthreads();
    if (t < QB && !done[t]) {
      const u32 c = cnt[t];
      if (c >= TOPK && c <= CAP) {
        done[t] = 1;
      } else {
        // bisection on monotone cnt(z): too few -> lower z, too many -> raise
        if (c < TOPK) zhi[t] = zc[t]; else zlo[t] = zc[t];
        zc[t] = 0.5f * (zlo[t] + zhi[t]);
        thrv[t] = zc[t] * snrm[t];
        s_more = 1;
      }
    }
    __syncthreads();
    if (!s_more) break;
  }

  // ---- selection: per wave 4 rows; 64 argmax passes (validated r2-r9) ----
  const int wid = t >> 6, lane = t & 63;
  #pragma unroll
  for (int rr = 0; rr < 4; ++rr) {
    const int row = wid + 8 * rr;
    const u32 n = min(cnt[row], (u32)CAP);   // n >= 64 by construction
    u64 slot[4];
    #pragma unroll
    for (int i = 0; i < 4; ++i) {
      const int idx = lane + 64 * i;
      u64 key = 0ULL;
      if (idx < (int)n)
        key = ((u64)candS[row][idx] << 32) | (u64)(4095 - (int)candJ[row][idx]);
      slot[i] = key;
    }
    const size_t obase = (((size_t)h << 12) | (size_t)(qc * QB + row)) << 6;
    for (int r = 0; r < TOPK; ++r) {
      const u64 lm = umax64(umax64(slot[0], slot[1]), umax64(slot[2], slot[3]));
      u64 v = lm;
      #pragma unroll
      for (int m = 1; m < 64; m <<= 1) {
        unsigned lo = (unsigned)(v & 0xffffffffULL);
        unsigned hi = (unsigned)(v >> 32);
        lo = (unsigned)__shfl_xor((int)lo, m, 64);
        hi = (unsigned)__shfl_xor((int)hi, m, 64);
        v = umax64(v, ((u64)hi << 32) | (u64)lo);
      }
      if (lm == v && v != 0ULL) {     // unique winner: keys globally distinct
        outg[obase + r] = 4095 - (int)(v & 0xFFFULL);
        #pragma unroll
        for (int i = 0; i < 4; ++i) if (slot[i] == v) slot[i] = 0ULL;
      }
    }
  }
}

extern "C" void kernel_launch(void* const* d_in, const int* in_sizes, int n_in,
                              void* d_out, int out_size, void* d_ws, size_t ws_size,
                              hipStream_t stream) {
  const float* q = (const float*)d_in[0];
  const float* k = (const float*)d_in[1];
  int* out = (int*)d_out;
  si_topk_kernel<<<dim3(HEADS * (SEQ / QB)), NT, 0, stream>>>(q, k, out);
}